// Round 15
// baseline (171.964 us; speedup 1.0000x reference)
//
#include <hip/hip_runtime.h>
#include <math.h>

#define ALPHA 0.2f

constexpr int CN0 = 512, CN1 = 2048, CN2 = 8192, CK = 33;
constexpr int CIN = 256, CHID = 128, CNH = 8;

using u16    = unsigned short;
using f32x4  = __attribute__((ext_vector_type(4))) float;
using bf16x8 = __attribute__((ext_vector_type(8))) short;

__device__ __forceinline__ u16 f2bf(float f) {
    unsigned u = __float_as_uint(f);
    u += 0x7fff + ((u >> 16) & 1);   // RNE
    return (u16)(u >> 16);
}
__device__ __forceinline__ float bf2f(u16 h) {
    return __uint_as_float(((unsigned)h) << 16);
}

#define GLD16(g, l)                                                        \
    __builtin_amdgcn_global_load_lds(                                      \
        (const __attribute__((address_space(1))) void*)(g),                \
        (__attribute__((address_space(3))) void*)(l), 16, 0, 0)

// ---------------------------------------------------------------------------
// prep: ALL mutually-independent input transforms in one dispatch.
// [0,2048): feats f32 -> fb bf16 (4/thread)
// [2048,2304): W1 [8][256][128] -> w1t [8][128][256] bf16
// [2304,2432): W2 [1024][128]   -> w2t [128][1024] bf16
// [2432,2448): pvec[h*2+half][j] = sum_c W1[h][j][c]*a1[h][half*128+c]
// ---------------------------------------------------------------------------
__global__ __launch_bounds__(256) void prep_k(const float* __restrict__ feats,
                                              u16* __restrict__ fb,
                                              const float* __restrict__ W1,
                                              u16* __restrict__ w1t,
                                              const float* __restrict__ W2,
                                              u16* __restrict__ w2t,
                                              const float* __restrict__ a1,
                                              float* __restrict__ pvec) {
    __shared__ float t[32][33];
    int b = blockIdx.x;
    if (b < 2048) {
        const int i = (b * 256 + threadIdx.x) * 4;
        const float4 v = *reinterpret_cast<const float4*>(feats + i);
        *reinterpret_cast<ushort4*>(fb + i) =
            make_ushort4(f2bf(v.x), f2bf(v.y), f2bf(v.z), f2bf(v.w));
        return;
    }
    if (b >= 2432) {   // pvec
        const int i = b - 2432;
        const int h = i >> 1, half = i & 1;
        const int j = threadIdx.x;
        const float* wrow = W1 + (size_t)h * CIN * CHID + (size_t)j * CHID;
        const float* ah   = a1 + h * 2 * CHID + half * CHID;
        float d = 0.f;
#pragma unroll 8
        for (int c = 0; c < CHID; ++c) d = fmaf(wrow[c], ah[c], d);
        pvec[(h * 2 + half) * CIN + j] = d;
        return;
    }
    b -= 2048;
    const float* ip;
    u16* op;
    int R, C, r0, c0;
    if (b < 256) {  // W1 head h
        const int h = b >> 5, w = b & 31;
        ip = W1 + (size_t)h * CIN * CHID;
        op = w1t + (size_t)h * CIN * CHID;
        R = CIN; C = CHID; r0 = (w >> 2) * 32; c0 = (w & 3) * 32;
    } else {        // W2
        b -= 256;
        ip = W2; op = w2t;
        R = CNH * CHID; C = CHID; r0 = (b >> 2) * 32; c0 = (b & 3) * 32;
    }
    const int tx = threadIdx.x & 31, ty = threadIdx.x >> 5;
#pragma unroll
    for (int i = 0; i < 4; ++i)
        t[ty + 8 * i][tx] = ip[(size_t)(r0 + ty + 8 * i) * C + c0 + tx];
    __syncthreads();
#pragma unroll
    for (int i = 0; i < 4; ++i)
        op[(size_t)(c0 + ty + 8 * i) * R + r0 + tx] = f2bf(t[tx][ty + 8 * i]);
}

// ---------------------------------------------------------------------------
// agg1g2: per-target scores (computed in-block from fb . pvec) + softmax +
// feats-gather-aggregate -> gb.  One 128-thread block per target.
// ---------------------------------------------------------------------------
__global__ __launch_bounds__(128) void agg1g2_k(const float* __restrict__ pvec,
                                                const int* __restrict__ src,
                                                const int* __restrict__ dst,
                                                const u16* __restrict__ fb,
                                                u16* __restrict__ gb) {
    __shared__ float sc[2][CK][CNH];   // [type(src/dst)][edge][head]
    __shared__ float wgt[CNH][CK];
    __shared__ int nds[2][CK];

    const int t    = blockIdx.x;
    const int tid  = threadIdx.x;
    const int wv   = tid >> 6;
    const int lane = tid & 63;

    if (tid < CK) {
        nds[0][tid] = src[t * CK + tid];
        nds[1][tid] = dst[t * CK + tid];
    }
    __syncthreads();

    // score phase: wave wv handles edges k = wv, wv+2, ...
    for (int k = wv; k < CK; k += 2) {
#pragma unroll
        for (int type = 0; type < 2; ++type) {
            const int n = nds[type][k];
            const ushort4 fv = *reinterpret_cast<const ushort4*>(
                fb + (size_t)n * CIN + lane * 4);
            const float f0 = bf2f(fv.x), f1 = bf2f(fv.y);
            const float f2 = bf2f(fv.z), f3 = bf2f(fv.w);
            float p0, p1, p2, p3, p4, p5, p6, p7;
#define DOT(H, P)                                                              \
            {                                                                  \
                const float4 pv = *reinterpret_cast<const float4*>(            \
                    pvec + (H * 2 + type) * CIN + lane * 4);                   \
                P = f0 * pv.x + f1 * pv.y + f2 * pv.z + f3 * pv.w;             \
            }
            DOT(0, p0) DOT(1, p1) DOT(2, p2) DOT(3, p3)
            DOT(4, p4) DOT(5, p5) DOT(6, p6) DOT(7, p7)
#undef DOT
#pragma unroll
            for (int m = 1; m < 64; m <<= 1) {
                p0 += __shfl_xor(p0, m); p1 += __shfl_xor(p1, m);
                p2 += __shfl_xor(p2, m); p3 += __shfl_xor(p3, m);
                p4 += __shfl_xor(p4, m); p5 += __shfl_xor(p5, m);
                p6 += __shfl_xor(p6, m); p7 += __shfl_xor(p7, m);
            }
            if (lane == 0) {
                sc[type][k][0] = p0; sc[type][k][1] = p1;
                sc[type][k][2] = p2; sc[type][k][3] = p3;
                sc[type][k][4] = p4; sc[type][k][5] = p5;
                sc[type][k][6] = p6; sc[type][k][7] = p7;
            }
        }
    }
    __syncthreads();

    // softmax per head (wave wv -> heads 4wv..4wv+3)
#pragma unroll
    for (int hh = 0; hh < 4; ++hh) {
        const int head = wv * 4 + hh;
        float e = -3.0e38f;
        if (lane < CK) {
            const float ee = sc[0][lane][head] + sc[1][lane][head];
            e = (ee > 0.f) ? ee : ALPHA * ee;
        }
        float m = e;
#pragma unroll
        for (int mm = 1; mm < 64; mm <<= 1) m = fmaxf(m, __shfl_xor(m, mm));
        const float p = (lane < CK) ? __expf(e - m) : 0.f;
        float s = p;
#pragma unroll
        for (int mm = 1; mm < 64; mm <<= 1) s += __shfl_xor(s, mm);
        if (lane < CK) wgt[head][lane] = p / s;
    }
    __syncthreads();

    // gather-aggregate phase (R11-proven)
    const int c2 = tid * 2;
    float acc[CNH][2];
#pragma unroll
    for (int h = 0; h < CNH; ++h) { acc[h][0] = 0.f; acc[h][1] = 0.f; }
#pragma unroll 4
    for (int k = 0; k < CK; ++k) {
        const unsigned w2v = *reinterpret_cast<const unsigned*>(
            fb + (size_t)nds[1][k] * CIN + c2);
        const float f0 = bf2f((u16)(w2v & 0xffff));
        const float f1 = bf2f((u16)(w2v >> 16));
#pragma unroll
        for (int h = 0; h < CNH; ++h) {
            const float wk = wgt[h][k];
            acc[h][0] = fmaf(wk, f0, acc[h][0]);
            acc[h][1] = fmaf(wk, f1, acc[h][1]);
        }
    }
#pragma unroll
    for (int h = 0; h < CNH; ++h) {
        const unsigned o = ((unsigned)f2bf(acc[h][1]) << 16) | f2bf(acc[h][0]);
        *reinterpret_cast<unsigned*>(gb + ((size_t)h * CN1 + t) * CIN + c2) = o;
    }
}

// ---------------------------------------------------------------------------
// fusedproj (R11-proven, 256 blocks): x = ELU(g_h @ W1_h) -> Xs (swizzled LDS)
// -> part[h] = Xs @ W2_h.  No sync tail.
// ---------------------------------------------------------------------------
__global__ __launch_bounds__(256) void fusedproj_k(const u16* __restrict__ gb,
                                                   const u16* __restrict__ w1t,
                                                   const u16* __restrict__ w2t,
                                                   float* __restrict__ part) {
    __shared__ __attribute__((aligned(16))) char smem[24576];

    const int tid  = threadIdx.x;
    const int lane = tid & 63;
    const int wave = tid >> 6;
    const int trow0 = blockIdx.x * 64;
    const int h     = blockIdx.y;
    const int wr = (wave >> 1) * 32;   // 0 / 32
    const int wc = (wave & 1) * 64;    // 0 / 64

    const u16* A  = gb  + (size_t)h * CN1 * CIN;
    const u16* Bt = w1t + (size_t)h * CHID * CIN;

    f32x4 acc[2][4];
#pragma unroll
    for (int m = 0; m < 2; ++m)
#pragma unroll
        for (int n = 0; n < 4; ++n) acc[m][n] = (f32x4){0.f, 0.f, 0.f, 0.f};

    const int r0c = tid >> 2;
    const int cs0 = tid & 3;
    const int c0  = (cs0 - (r0c >> 1)) & 3;
    const int r1c = r0c + 64;

    const u16* ga0 = A + (size_t)(trow0 + r0c) * CIN + c0 * 8;
    const u16* gb0 = Bt + (size_t)r0c * CIN + c0 * 8;
    const u16* gb1 = Bt + (size_t)r1c * CIN + c0 * 8;

    auto STAGE = [&](int s) {
        const int k0 = s * 32;
        char* base = smem + (s & 1) * 12288;
        u16* as = (u16*)base + wave * 512;
        u16* bs = (u16*)(base + 4096) + wave * 512;
        GLD16(ga0 + k0, as);
        GLD16(gb0 + k0, bs);
        GLD16(gb1 + k0, bs + 2048);
    };

    STAGE(0);
    __syncthreads();

    for (int s = 0; s < 8; ++s) {
        if (s + 1 < 8) STAGE(s + 1);

        const u16* Acur = (const u16*)(smem + (s & 1) * 12288);
        const u16* Bcur = Acur + 2048;

        bf16x8 af[2], bfr[4];
#pragma unroll
        for (int m = 0; m < 2; ++m) {
            const int rt = wr + m * 16 + (lane & 15);
            const int cs = ((lane >> 4) + (rt >> 1)) & 3;
            af[m] = *reinterpret_cast<const bf16x8*>(Acur + rt * 32 + cs * 8);
        }
#pragma unroll
        for (int n = 0; n < 4; ++n) {
            const int rt2 = wc + n * 16 + (lane & 15);
            const int cs2 = ((lane >> 4) + (rt2 >> 1)) & 3;
            bfr[n] = *reinterpret_cast<const bf16x8*>(Bcur + rt2 * 32 + cs2 * 8);
        }
#pragma unroll
        for (int m = 0; m < 2; ++m)
#pragma unroll
            for (int n = 0; n < 4; ++n)
                acc[m][n] = __builtin_amdgcn_mfma_f32_16x16x32_bf16(
                    af[m], bfr[n], acc[m][n], 0, 0, 0);

        __syncthreads();
    }

    // ELU -> bf16 -> Xs (XOR-chunk swizzle)
    u16* Xs = (u16*)smem;
#pragma unroll
    for (int m = 0; m < 2; ++m) {
        const int rr = wr + m * 16 + (lane >> 4) * 4;
#pragma unroll
        for (int n = 0; n < 4; ++n) {
            const int cc = wc + n * 16 + (lane & 15);
#pragma unroll
            for (int q = 0; q < 4; ++q) {
                float v = acc[m][n][q];
                v = (v > 0.f) ? v : __expf(v) - 1.f;
                const int r = rr + q;
                Xs[r * 128 + ((((cc >> 3) ^ (r & 7)) << 3) | (cc & 7))] = f2bf(v);
            }
        }
    }
    __syncthreads();

    // GEMM2: part[h] = Xs @ W2_h (K=128)
    f32x4 acc2[2][4];
#pragma unroll
    for (int m = 0; m < 2; ++m)
#pragma unroll
        for (int n = 0; n < 4; ++n) acc2[m][n] = (f32x4){0.f, 0.f, 0.f, 0.f};

#pragma unroll
    for (int ks = 0; ks < 4; ++ks) {
        bf16x8 a2f[2], b2f[4];
#pragma unroll
        for (int m = 0; m < 2; ++m) {
            const int rt = wr + m * 16 + (lane & 15);
            const int k0 = ks * 32 + (lane >> 4) * 8;
            a2f[m] = *reinterpret_cast<const bf16x8*>(
                Xs + rt * 128 + (((k0 >> 3) ^ (rt & 7)) << 3));
        }
#pragma unroll
        for (int n = 0; n < 4; ++n) {
            const int rb = wc + n * 16 + (lane & 15);
            b2f[n] = *reinterpret_cast<const bf16x8*>(
                w2t + (size_t)rb * (CNH * CHID) + h * CHID + ks * 32 + (lane >> 4) * 8);
        }
#pragma unroll
        for (int m = 0; m < 2; ++m)
#pragma unroll
            for (int n = 0; n < 4; ++n)
                acc2[m][n] = __builtin_amdgcn_mfma_f32_16x16x32_bf16(
                    a2f[m], b2f[n], acc2[m][n], 0, 0, 0);
    }

#pragma unroll
    for (int m = 0; m < 2; ++m) {
        const int rr = trow0 + wr + m * 16 + (lane >> 4) * 4;
#pragma unroll
        for (int n = 0; n < 4; ++n) {
            const int cc = wc + n * 16 + (lane & 15);
#pragma unroll
            for (int q = 0; q < 4; ++q)
                part[((size_t)h * CN1 + rr + q) * CHID + cc] = acc2[m][n][q];
        }
    }
}

// ---------------------------------------------------------------------------
// final: per-target on-the-fly split-K reduce + scores + softmax + aggregate
// + ELU -> out.  One 128-thread block per target (512 blocks).
// dst rows reduced into LDS (reused for score AND aggregate); src rows
// reduced inline for their dot only.
// ---------------------------------------------------------------------------
__global__ __launch_bounds__(128) void final_k(const float* __restrict__ part,
                                               const float* __restrict__ a2,
                                               const int* __restrict__ src,
                                               const int* __restrict__ dst,
                                               float* __restrict__ out) {
    __shared__ float h2row[CK][CHID];   // 16.9 KB
    __shared__ float e1[CK], e2[CK], wgt[CK];
    __shared__ int nds[2][CK];

    const int t    = blockIdx.x;
    const int tid  = threadIdx.x;
    const int wv   = tid >> 6;
    const int lane = tid & 63;

    if (tid < CK) {
        nds[0][tid] = src[t * CK + tid];
        nds[1][tid] = dst[t * CK + tid];
    }
    __syncthreads();

    // Phase A: reduce 8 partials of each dst row -> LDS (thread = col)
    for (int k = 0; k < CK; ++k) {
        const int dv = nds[1][k];
        float x = 0.f;
#pragma unroll
        for (int sp = 0; sp < 8; ++sp)
            x += part[((size_t)sp * CN1 + dv) * CHID + tid];
        h2row[k][tid] = x;
    }
    __syncthreads();

    // Phase B: score dots. wave0: src rows (inline reduce); wave1: dst from LDS
    if (wv == 0) {
        for (int k = 0; k < CK; ++k) {
            const int sv = nds[0][k];
            const int j = lane * 2;
            float x0 = 0.f, x1 = 0.f;
#pragma unroll
            for (int sp = 0; sp < 8; ++sp) {
                const float2 v = *reinterpret_cast<const float2*>(
                    part + ((size_t)sp * CN1 + sv) * CHID + j);
                x0 += v.x; x1 += v.y;
            }
            float d = x0 * a2[j] + x1 * a2[j + 1];
#pragma unroll
            for (int m = 1; m < 64; m <<= 1) d += __shfl_xor(d, m);
            if (lane == 0) e1[k] = d;
        }
    } else {
        for (int k = 0; k < CK; ++k) {
            const int j = lane * 2;
            float d = h2row[k][j] * a2[CHID + j] + h2row[k][j + 1] * a2[CHID + j + 1];
#pragma unroll
            for (int m = 1; m < 64; m <<= 1) d += __shfl_xor(d, m);
            if (lane == 0) e2[k] = d;
        }
    }
    __syncthreads();

    // Phase C: softmax over 33 edges (wave 0)
    if (wv == 0) {
        float e = -3.0e38f;
        if (lane < CK) {
            const float ee = e1[lane] + e2[lane];
            e = (ee > 0.f) ? ee : ALPHA * ee;
        }
        float m = e;
#pragma unroll
        for (int mm = 1; mm < 64; mm <<= 1) m = fmaxf(m, __shfl_xor(m, mm));
        const float p = (lane < CK) ? __expf(e - m) : 0.f;
        float s = p;
#pragma unroll
        for (int mm = 1; mm < 64; mm <<= 1) s += __shfl_xor(s, mm);
        if (lane < CK) wgt[lane] = p / s;
    }
    __syncthreads();

    // Phase D: aggregate (thread = col) + ELU
    float acc = 0.f;
#pragma unroll
    for (int k = 0; k < CK; ++k)
        acc = fmaf(wgt[k], h2row[k][tid], acc);
    out[(size_t)t * CHID + tid] = (acc > 0.f) ? acc : __expf(acc) - 1.f;
}

// ---------------------------------------------------------------------------
extern "C" void kernel_launch(void* const* d_in, const int* in_sizes, int n_in,
                              void* d_out, int out_size, void* d_ws, size_t ws_size,
                              hipStream_t stream) {
    const float* feats = (const float*)d_in[0];
    const float* W1    = (const float*)d_in[1];
    const float* a1    = (const float*)d_in[2];
    const float* W2    = (const float*)d_in[3];
    const float* a2    = (const float*)d_in[4];
    const int*   src1  = (const int*)d_in[5];
    const int*   dst1  = (const int*)d_in[6];
    const int*   src2  = (const int*)d_in[8];
    const int*   dst2  = (const int*)d_in[9];
    float* out = (float*)d_out;

    char* w = (char*)d_ws;
    u16*   fb   = (u16*)w;                 w += (size_t)CN2 * CIN * 2;          // 4 MB
    u16*   w1t  = (u16*)w;                 w += (size_t)CNH * CIN * CHID * 2;
    u16*   w2t  = (u16*)w;                 w += (size_t)CNH * CHID * CHID * 2;
    float* pvec = (float*)w;               w += (size_t)CNH * 2 * CIN * 4;
    u16*   gb   = (u16*)w;                 w += (size_t)CNH * CN1 * CIN * 2;    // 8 MB
    float* part = (float*)w;               w += (size_t)8 * CN1 * CHID * 4;     // 8 MB

    // 1. all input transforms (independent)
    prep_k<<<dim3(2048 + 256 + 128 + 16), 256, 0, stream>>>(
        feats, fb, W1, w1t, W2, w2t, a1, pvec);

    // 2. per-target scores + softmax + feats-aggregate -> gb
    agg1g2_k<<<dim3(CN1), 128, 0, stream>>>(pvec, src1, dst1, fb, gb);

    // 3. part[h] = ELU(g_h @ W1_h) @ W2_h
    fusedproj_k<<<dim3(CN1 / 64, CNH), 256, 0, stream>>>(gb, w1t, w2t, part);

    // 4. on-the-fly reduce + scores + softmax + aggregate + ELU -> out
    final_k<<<dim3(CN0), 128, 0, stream>>>(part, a2, src2, dst2, out);
}

// Round 16
// 108.691 us; speedup vs baseline: 1.5821x; 1.5821x over previous
//
#include <hip/hip_runtime.h>
#include <math.h>

#define ALPHA 0.2f

constexpr int CN0 = 512, CN1 = 2048, CN2 = 8192, CK = 33;
constexpr int CIN = 256, CHID = 128, CNH = 8;

using u16    = unsigned short;
using f32x4  = __attribute__((ext_vector_type(4))) float;
using bf16x8 = __attribute__((ext_vector_type(8))) short;

__device__ __forceinline__ u16 f2bf(float f) {
    unsigned u = __float_as_uint(f);
    u += 0x7fff + ((u >> 16) & 1);   // RNE
    return (u16)(u >> 16);
}
__device__ __forceinline__ float bf2f(u16 h) {
    return __uint_as_float(((unsigned)h) << 16);
}

#define GLD16(g, l)                                                        \
    __builtin_amdgcn_global_load_lds(                                      \
        (const __attribute__((address_space(1))) void*)(g),                \
        (__attribute__((address_space(3))) void*)(l), 16, 0, 0)

// ---------------------------------------------------------------------------
// prep: ALL mutually-independent input transforms in one dispatch. (R15-proven)
// [0,2048): feats f32 -> fb bf16; [2048,2304): W1 T; [2304,2432): W2 T;
// [2432,2448): pvec[h*2+half][j] = sum_c W1[h][j][c]*a1[h][half*128+c]
// ---------------------------------------------------------------------------
__global__ __launch_bounds__(256) void prep_k(const float* __restrict__ feats,
                                              u16* __restrict__ fb,
                                              const float* __restrict__ W1,
                                              u16* __restrict__ w1t,
                                              const float* __restrict__ W2,
                                              u16* __restrict__ w2t,
                                              const float* __restrict__ a1,
                                              float* __restrict__ pvec) {
    __shared__ float t[32][33];
    int b = blockIdx.x;
    if (b < 2048) {
        const int i = (b * 256 + threadIdx.x) * 4;
        const float4 v = *reinterpret_cast<const float4*>(feats + i);
        *reinterpret_cast<ushort4*>(fb + i) =
            make_ushort4(f2bf(v.x), f2bf(v.y), f2bf(v.z), f2bf(v.w));
        return;
    }
    if (b >= 2432) {   // pvec
        const int i = b - 2432;
        const int h = i >> 1, half = i & 1;
        const int j = threadIdx.x;
        const float* wrow = W1 + (size_t)h * CIN * CHID + (size_t)j * CHID;
        const float* ah   = a1 + h * 2 * CHID + half * CHID;
        float d = 0.f;
#pragma unroll 8
        for (int c = 0; c < CHID; ++c) d = fmaf(wrow[c], ah[c], d);
        pvec[(h * 2 + half) * CIN + j] = d;
        return;
    }
    b -= 2048;
    const float* ip;
    u16* op;
    int R, C, r0, c0;
    if (b < 256) {  // W1 head h
        const int h = b >> 5, w = b & 31;
        ip = W1 + (size_t)h * CIN * CHID;
        op = w1t + (size_t)h * CIN * CHID;
        R = CIN; C = CHID; r0 = (w >> 2) * 32; c0 = (w & 3) * 32;
    } else {        // W2
        b -= 256;
        ip = W2; op = w2t;
        R = CNH * CHID; C = CHID; r0 = (b >> 2) * 32; c0 = (b & 3) * 32;
    }
    const int tx = threadIdx.x & 31, ty = threadIdx.x >> 5;
#pragma unroll
    for (int i = 0; i < 4; ++i)
        t[ty + 8 * i][tx] = ip[(size_t)(r0 + ty + 8 * i) * C + c0 + tx];
    __syncthreads();
#pragma unroll
    for (int i = 0; i < 4; ++i)
        op[(size_t)(c0 + ty + 8 * i) * R + r0 + tx] = f2bf(t[tx][ty + 8 * i]);
}

// ---------------------------------------------------------------------------
// sgemm1 (R10-proven): s1[h][n] = fb[n].pvec[h][0], s2 = fb[n].pvec[h][1]
// one wave per node, 2048 blocks.
// ---------------------------------------------------------------------------
__global__ __launch_bounds__(256) void sgemm1_k(const u16* __restrict__ fb,
                                                const float* __restrict__ pvec,
                                                float* __restrict__ s1,
                                                float* __restrict__ s2) {
    const int node = (blockIdx.x * 256 + threadIdx.x) >> 6;
    const int lane = threadIdx.x & 63;
    const ushort4 hv = *reinterpret_cast<const ushort4*>(fb + (size_t)node * CIN + lane * 4);
    const float v0 = bf2f(hv.x), v1 = bf2f(hv.y), v2 = bf2f(hv.z), v3 = bf2f(hv.w);
#pragma unroll
    for (int h = 0; h < CNH; ++h) {
        const float4 p1 = *reinterpret_cast<const float4*>(pvec + (h * 2 + 0) * CIN + lane * 4);
        const float4 p2 = *reinterpret_cast<const float4*>(pvec + (h * 2 + 1) * CIN + lane * 4);
        float d1 = v0 * p1.x + v1 * p1.y + v2 * p1.z + v3 * p1.w;
        float d2 = v0 * p2.x + v1 * p2.y + v2 * p2.z + v3 * p2.w;
#pragma unroll
        for (int m = 1; m < 64; m <<= 1) {
            d1 += __shfl_xor(d1, m);
            d2 += __shfl_xor(d2, m);
        }
        if (lane == 0) {
            s1[h * CN2 + node] = d1;
            s2[h * CN2 + node] = d2;
        }
    }
}

// ---------------------------------------------------------------------------
// agg1g (R11-proven): softmax + feats-gather-aggregate -> g[h][t][c] bf16.
// ---------------------------------------------------------------------------
__global__ __launch_bounds__(128) void agg1g_k(const float* __restrict__ s1,
                                               const float* __restrict__ s2,
                                               const int* __restrict__ src,
                                               const int* __restrict__ dst,
                                               const u16* __restrict__ fb,
                                               u16* __restrict__ gb) {
    __shared__ float wgt[CNH][CK];
    __shared__ int dsts[CK];

    const int t    = blockIdx.x;
    const int tid  = threadIdx.x;
    const int wv   = tid >> 6;
    const int lane = tid & 63;

    int sv = 0, dv = 0;
    if (lane < CK) {
        sv = src[t * CK + lane];
        dv = dst[t * CK + lane];
        if (tid < CK) dsts[tid] = dv;
    }
#pragma unroll
    for (int hh = 0; hh < 4; ++hh) {
        const int head = wv * 4 + hh;
        float e = -3.0e38f;
        if (lane < CK) {
            const float ee = s1[head * CN2 + sv] + s2[head * CN2 + dv];
            e = (ee > 0.f) ? ee : ALPHA * ee;
        }
        float m = e;
#pragma unroll
        for (int mm = 1; mm < 64; mm <<= 1) m = fmaxf(m, __shfl_xor(m, mm));
        const float p = (lane < CK) ? __expf(e - m) : 0.f;
        float s = p;
#pragma unroll
        for (int mm = 1; mm < 64; mm <<= 1) s += __shfl_xor(s, mm);
        if (lane < CK) wgt[head][lane] = p / s;
    }
    __syncthreads();

    const int c2 = tid * 2;
    float acc[CNH][2];
#pragma unroll
    for (int h = 0; h < CNH; ++h) { acc[h][0] = 0.f; acc[h][1] = 0.f; }
#pragma unroll 4
    for (int k = 0; k < CK; ++k) {
        const unsigned w2v = *reinterpret_cast<const unsigned*>(
            fb + (size_t)dsts[k] * CIN + c2);
        const float f0 = bf2f((u16)(w2v & 0xffff));
        const float f1 = bf2f((u16)(w2v >> 16));
#pragma unroll
        for (int h = 0; h < CNH; ++h) {
            const float wk = wgt[h][k];
            acc[h][0] = fmaf(wk, f0, acc[h][0]);
            acc[h][1] = fmaf(wk, f1, acc[h][1]);
        }
    }
#pragma unroll
    for (int h = 0; h < CNH; ++h) {
        const unsigned o = ((unsigned)f2bf(acc[h][1]) << 16) | f2bf(acc[h][0]);
        *reinterpret_cast<unsigned*>(gb + ((size_t)h * CN1 + t) * CIN + c2) = o;
    }
}

// ---------------------------------------------------------------------------
// fusedproj (R11-proven, 256 blocks): x = ELU(g_h @ W1_h) -> Xs (swizzled LDS)
// -> part[h] = Xs @ W2_h.
// ---------------------------------------------------------------------------
__global__ __launch_bounds__(256) void fusedproj_k(const u16* __restrict__ gb,
                                                   const u16* __restrict__ w1t,
                                                   const u16* __restrict__ w2t,
                                                   float* __restrict__ part) {
    __shared__ __attribute__((aligned(16))) char smem[24576];

    const int tid  = threadIdx.x;
    const int lane = tid & 63;
    const int wave = tid >> 6;
    const int trow0 = blockIdx.x * 64;
    const int h     = blockIdx.y;
    const int wr = (wave >> 1) * 32;   // 0 / 32
    const int wc = (wave & 1) * 64;    // 0 / 64

    const u16* A  = gb  + (size_t)h * CN1 * CIN;
    const u16* Bt = w1t + (size_t)h * CHID * CIN;

    f32x4 acc[2][4];
#pragma unroll
    for (int m = 0; m < 2; ++m)
#pragma unroll
        for (int n = 0; n < 4; ++n) acc[m][n] = (f32x4){0.f, 0.f, 0.f, 0.f};

    const int r0c = tid >> 2;
    const int cs0 = tid & 3;
    const int c0  = (cs0 - (r0c >> 1)) & 3;
    const int r1c = r0c + 64;

    const u16* ga0 = A + (size_t)(trow0 + r0c) * CIN + c0 * 8;
    const u16* gb0 = Bt + (size_t)r0c * CIN + c0 * 8;
    const u16* gb1 = Bt + (size_t)r1c * CIN + c0 * 8;

    auto STAGE = [&](int s) {
        const int k0 = s * 32;
        char* base = smem + (s & 1) * 12288;
        u16* as = (u16*)base + wave * 512;
        u16* bs = (u16*)(base + 4096) + wave * 512;
        GLD16(ga0 + k0, as);
        GLD16(gb0 + k0, bs);
        GLD16(gb1 + k0, bs + 2048);
    };

    STAGE(0);
    __syncthreads();

    for (int s = 0; s < 8; ++s) {
        if (s + 1 < 8) STAGE(s + 1);

        const u16* Acur = (const u16*)(smem + (s & 1) * 12288);
        const u16* Bcur = Acur + 2048;

        bf16x8 af[2], bfr[4];
#pragma unroll
        for (int m = 0; m < 2; ++m) {
            const int rt = wr + m * 16 + (lane & 15);
            const int cs = ((lane >> 4) + (rt >> 1)) & 3;
            af[m] = *reinterpret_cast<const bf16x8*>(Acur + rt * 32 + cs * 8);
        }
#pragma unroll
        for (int n = 0; n < 4; ++n) {
            const int rt2 = wc + n * 16 + (lane & 15);
            const int cs2 = ((lane >> 4) + (rt2 >> 1)) & 3;
            bfr[n] = *reinterpret_cast<const bf16x8*>(Bcur + rt2 * 32 + cs2 * 8);
        }
#pragma unroll
        for (int m = 0; m < 2; ++m)
#pragma unroll
            for (int n = 0; n < 4; ++n)
                acc[m][n] = __builtin_amdgcn_mfma_f32_16x16x32_bf16(
                    af[m], bfr[n], acc[m][n], 0, 0, 0);

        __syncthreads();
    }

    // ELU -> bf16 -> Xs (XOR-chunk swizzle)
    u16* Xs = (u16*)smem;
#pragma unroll
    for (int m = 0; m < 2; ++m) {
        const int rr = wr + m * 16 + (lane >> 4) * 4;
#pragma unroll
        for (int n = 0; n < 4; ++n) {
            const int cc = wc + n * 16 + (lane & 15);
#pragma unroll
            for (int q = 0; q < 4; ++q) {
                float v = acc[m][n][q];
                v = (v > 0.f) ? v : __expf(v) - 1.f;
                const int r = rr + q;
                Xs[r * 128 + ((((cc >> 3) ^ (r & 7)) << 3) | (cc & 7))] = f2bf(v);
            }
        }
    }
    __syncthreads();

    // GEMM2: part[h] = Xs @ W2_h (K=128)
    f32x4 acc2[2][4];
#pragma unroll
    for (int m = 0; m < 2; ++m)
#pragma unroll
        for (int n = 0; n < 4; ++n) acc2[m][n] = (f32x4){0.f, 0.f, 0.f, 0.f};

#pragma unroll
    for (int ks = 0; ks < 4; ++ks) {
        bf16x8 a2f[2], b2f[4];
#pragma unroll
        for (int m = 0; m < 2; ++m) {
            const int rt = wr + m * 16 + (lane & 15);
            const int k0 = ks * 32 + (lane >> 4) * 8;
            a2f[m] = *reinterpret_cast<const bf16x8*>(
                Xs + rt * 128 + (((k0 >> 3) ^ (rt & 7)) << 3));
        }
#pragma unroll
        for (int n = 0; n < 4; ++n) {
            const int rb = wc + n * 16 + (lane & 15);
            b2f[n] = *reinterpret_cast<const bf16x8*>(
                w2t + (size_t)rb * (CNH * CHID) + h * CHID + ks * 32 + (lane >> 4) * 8);
        }
#pragma unroll
        for (int m = 0; m < 2; ++m)
#pragma unroll
            for (int n = 0; n < 4; ++n)
                acc2[m][n] = __builtin_amdgcn_mfma_f32_16x16x32_bf16(
                    a2f[m], b2f[n], acc2[m][n], 0, 0, 0);
    }

#pragma unroll
    for (int m = 0; m < 2; ++m) {
        const int rr = trow0 + wr + m * 16 + (lane >> 4) * 4;
#pragma unroll
        for (int n = 0; n < 4; ++n) {
            const int cc = wc + n * 16 + (lane & 15);
#pragma unroll
            for (int q = 0; q < 4; ++q)
                part[((size_t)h * CN1 + rr + q) * CHID + cc] = acc2[m][n][q];
        }
    }
}

// ---------------------------------------------------------------------------
// final (R15-proven): per-target on-the-fly split-K reduce + scores + softmax
// + aggregate + ELU -> out.  One 128-thread block per target.
// ---------------------------------------------------------------------------
__global__ __launch_bounds__(128) void final_k(const float* __restrict__ part,
                                               const float* __restrict__ a2,
                                               const int* __restrict__ src,
                                               const int* __restrict__ dst,
                                               float* __restrict__ out) {
    __shared__ float h2row[CK][CHID];
    __shared__ float e1[CK], e2[CK], wgt[CK];
    __shared__ int nds[2][CK];

    const int t    = blockIdx.x;
    const int tid  = threadIdx.x;
    const int wv   = tid >> 6;
    const int lane = tid & 63;

    if (tid < CK) {
        nds[0][tid] = src[t * CK + tid];
        nds[1][tid] = dst[t * CK + tid];
    }
    __syncthreads();

    // Phase A: reduce 8 partials of each dst row -> LDS (thread = col)
    for (int k = 0; k < CK; ++k) {
        const int dv = nds[1][k];
        float x = 0.f;
#pragma unroll
        for (int sp = 0; sp < 8; ++sp)
            x += part[((size_t)sp * CN1 + dv) * CHID + tid];
        h2row[k][tid] = x;
    }
    __syncthreads();

    // Phase B: score dots. wave0: src rows (inline reduce); wave1: dst from LDS
    if (wv == 0) {
        for (int k = 0; k < CK; ++k) {
            const int sv = nds[0][k];
            const int j = lane * 2;
            float x0 = 0.f, x1 = 0.f;
#pragma unroll
            for (int sp = 0; sp < 8; ++sp) {
                const float2 v = *reinterpret_cast<const float2*>(
                    part + ((size_t)sp * CN1 + sv) * CHID + j);
                x0 += v.x; x1 += v.y;
            }
            float d = x0 * a2[j] + x1 * a2[j + 1];
#pragma unroll
            for (int m = 1; m < 64; m <<= 1) d += __shfl_xor(d, m);
            if (lane == 0) e1[k] = d;
        }
    } else {
        for (int k = 0; k < CK; ++k) {
            const int j = lane * 2;
            float d = h2row[k][j] * a2[CHID + j] + h2row[k][j + 1] * a2[CHID + j + 1];
#pragma unroll
            for (int m = 1; m < 64; m <<= 1) d += __shfl_xor(d, m);
            if (lane == 0) e2[k] = d;
        }
    }
    __syncthreads();

    // Phase C: softmax over 33 edges (wave 0)
    if (wv == 0) {
        float e = -3.0e38f;
        if (lane < CK) {
            const float ee = e1[lane] + e2[lane];
            e = (ee > 0.f) ? ee : ALPHA * ee;
        }
        float m = e;
#pragma unroll
        for (int mm = 1; mm < 64; mm <<= 1) m = fmaxf(m, __shfl_xor(m, mm));
        const float p = (lane < CK) ? __expf(e - m) : 0.f;
        float s = p;
#pragma unroll
        for (int mm = 1; mm < 64; mm <<= 1) s += __shfl_xor(s, mm);
        if (lane < CK) wgt[lane] = p / s;
    }
    __syncthreads();

    // Phase D: aggregate (thread = col) + ELU
    float acc = 0.f;
#pragma unroll
    for (int k = 0; k < CK; ++k)
        acc = fmaf(wgt[k], h2row[k][tid], acc);
    out[(size_t)t * CHID + tid] = (acc > 0.f) ? acc : __expf(acc) - 1.f;
}

// ---------------------------------------------------------------------------
extern "C" void kernel_launch(void* const* d_in, const int* in_sizes, int n_in,
                              void* d_out, int out_size, void* d_ws, size_t ws_size,
                              hipStream_t stream) {
    const float* feats = (const float*)d_in[0];
    const float* W1    = (const float*)d_in[1];
    const float* a1    = (const float*)d_in[2];
    const float* W2    = (const float*)d_in[3];
    const float* a2    = (const float*)d_in[4];
    const int*   src1  = (const int*)d_in[5];
    const int*   dst1  = (const int*)d_in[6];
    const int*   src2  = (const int*)d_in[8];
    const int*   dst2  = (const int*)d_in[9];
    float* out = (float*)d_out;

    char* w = (char*)d_ws;
    u16*   fb   = (u16*)w;                 w += (size_t)CN2 * CIN * 2;          // 4 MB
    u16*   w1t  = (u16*)w;                 w += (size_t)CNH * CIN * CHID * 2;
    u16*   w2t  = (u16*)w;                 w += (size_t)CNH * CHID * CHID * 2;
    float* pvec = (float*)w;               w += (size_t)CNH * 2 * CIN * 4;
    float* s1   = (float*)w;               w += (size_t)CNH * CN2 * 4;
    float* s2   = (float*)w;               w += (size_t)CNH * CN2 * 4;
    u16*   gb   = (u16*)w;                 w += (size_t)CNH * CN1 * CIN * 2;    // 8 MB
    float* part = (float*)w;               w += (size_t)8 * CN1 * CHID * 4;     // 8 MB

    // 1. all input transforms (independent)
    prep_k<<<dim3(2048 + 256 + 128 + 16), 256, 0, stream>>>(
        feats, fb, W1, w1t, W2, w2t, a1, pvec);

    // 2. all-node layer-1 scores (one wave per node)
    sgemm1_k<<<dim3(CN2 / 4), 256, 0, stream>>>(fb, pvec, s1, s2);

    // 3. layer-1 softmax + feats-aggregate -> gb
    agg1g_k<<<dim3(CN1), 128, 0, stream>>>(s1, s2, src1, dst1, fb, gb);

    // 4. part[h] = ELU(g_h @ W1_h) @ W2_h
    fusedproj_k<<<dim3(CN1 / 64, CNH), 256, 0, stream>>>(gb, w1t, w2t, part);

    // 5. on-the-fly reduce + scores + softmax + aggregate + ELU -> out
    final_k<<<dim3(CN0), 128, 0, stream>>>(part, a2, src2, dst2, out);
}

// Round 17
// 51.316 us; speedup vs baseline: 3.3511x; 2.1181x over previous
//
#include <hip/hip_runtime.h>
#include <math.h>

#define ALPHA 0.2f

constexpr int CN0 = 512, CN1 = 2048, CN2 = 8192, CK = 33;
constexpr int CIN = 256, CHID = 128, CNH = 8;

using u16    = unsigned short;
using f32x4  = __attribute__((ext_vector_type(4))) float;
using bf16x8 = __attribute__((ext_vector_type(8))) short;

__device__ __forceinline__ u16 f2bf(float f) {
    unsigned u = __float_as_uint(f);
    u += 0x7fff + ((u >> 16) & 1);   // RNE
    return (u16)(u >> 16);
}
__device__ __forceinline__ float bf2f(u16 h) {
    return __uint_as_float(((unsigned)h) << 16);
}

#define GLD16(g, l)                                                        \
    __builtin_amdgcn_global_load_lds(                                      \
        (const __attribute__((address_space(1))) void*)(g),                \
        (__attribute__((address_space(3))) void*)(l), 16, 0, 0)

// ---------------------------------------------------------------------------
// prep2: W1/W2 transpose-convert + pvec = W1_h @ a1 halves.
// blocks [0,256): W1 T; [256,384): W2 T; [384,400): pvec
// ---------------------------------------------------------------------------
__global__ __launch_bounds__(256) void prep2_k(const float* __restrict__ W1,
                                               u16* __restrict__ w1t,
                                               const float* __restrict__ W2,
                                               u16* __restrict__ w2t,
                                               const float* __restrict__ a1,
                                               float* __restrict__ pvec) {
    __shared__ float t[32][33];
    int b = blockIdx.x;
    if (b >= 384) {   // pvec: 16 blocks, one per (head, half)
        const int i = b - 384;
        const int h = i >> 1, half = i & 1;
        const int j = threadIdx.x;   // 0..255
        const float* wrow = W1 + (size_t)h * CIN * CHID + (size_t)j * CHID;
        const float* ah   = a1 + h * 2 * CHID + half * CHID;
        float d = 0.f;
#pragma unroll 8
        for (int c = 0; c < CHID; ++c) d = fmaf(wrow[c], ah[c], d);
        pvec[(h * 2 + half) * CIN + j] = d;
        return;
    }
    const float* ip;
    u16* op;
    int R, C, r0, c0;
    if (b < 256) {  // W1 head h
        const int h = b >> 5, w = b & 31;
        ip = W1 + (size_t)h * CIN * CHID;
        op = w1t + (size_t)h * CIN * CHID;
        R = CIN; C = CHID; r0 = (w >> 2) * 32; c0 = (w & 3) * 32;
    } else {        // W2
        b -= 256;
        ip = W2; op = w2t;
        R = CNH * CHID; C = CHID; r0 = (b >> 2) * 32; c0 = (b & 3) * 32;
    }
    const int tx = threadIdx.x & 31, ty = threadIdx.x >> 5;
#pragma unroll
    for (int i = 0; i < 4; ++i)
        t[ty + 8 * i][tx] = ip[(size_t)(r0 + ty + 8 * i) * C + c0 + tx];
    __syncthreads();
#pragma unroll
    for (int i = 0; i < 4; ++i)
        op[(size_t)(c0 + ty + 8 * i) * R + r0 + tx] = f2bf(t[tx][ty + 8 * i]);
}

// ---------------------------------------------------------------------------
// fsc: feats f32 -> fb bf16 AND all-head scores in one pass.
// one wave per node (4 nodes / 256-thread block).
// ---------------------------------------------------------------------------
__global__ __launch_bounds__(256) void fsc_k(const float* __restrict__ feats,
                                             u16* __restrict__ fb,
                                             const float* __restrict__ pvec,
                                             float* __restrict__ s1,
                                             float* __restrict__ s2) {
    const int node = (blockIdx.x * 256 + threadIdx.x) >> 6;
    const int lane = threadIdx.x & 63;
    const float4 v = *reinterpret_cast<const float4*>(feats + (size_t)node * CIN + lane * 4);
    *reinterpret_cast<ushort4*>(fb + (size_t)node * CIN + lane * 4) =
        make_ushort4(f2bf(v.x), f2bf(v.y), f2bf(v.z), f2bf(v.w));
#pragma unroll
    for (int h = 0; h < CNH; ++h) {
        const float4 p1 = *reinterpret_cast<const float4*>(pvec + (h * 2 + 0) * CIN + lane * 4);
        const float4 p2 = *reinterpret_cast<const float4*>(pvec + (h * 2 + 1) * CIN + lane * 4);
        float d1 = v.x * p1.x + v.y * p1.y + v.z * p1.z + v.w * p1.w;
        float d2 = v.x * p2.x + v.y * p2.y + v.z * p2.z + v.w * p2.w;
#pragma unroll
        for (int m = 1; m < 64; m <<= 1) {
            d1 += __shfl_xor(d1, m);
            d2 += __shfl_xor(d2, m);
        }
        if (lane == 0) {
            s1[h * CN2 + node] = d1;
            s2[h * CN2 + node] = d2;
        }
    }
}

// ---------------------------------------------------------------------------
// layer-1 softmax + feats-gather-aggregate -> g[h][t][c] bf16.
// One 128-thread block per target.
// ---------------------------------------------------------------------------
__global__ __launch_bounds__(128) void agg1g_k(const float* __restrict__ s1,
                                               const float* __restrict__ s2,
                                               const int* __restrict__ src,
                                               const int* __restrict__ dst,
                                               const u16* __restrict__ fb,
                                               u16* __restrict__ gb) {
    __shared__ float wgt[CNH][CK];
    __shared__ int dsts[CK];

    const int t    = blockIdx.x;
    const int tid  = threadIdx.x;
    const int wv   = tid >> 6;
    const int lane = tid & 63;

    int sv = 0, dv = 0;
    if (lane < CK) {
        sv = src[t * CK + lane];
        dv = dst[t * CK + lane];
        if (tid < CK) dsts[tid] = dv;
    }
#pragma unroll
    for (int hh = 0; hh < 4; ++hh) {
        const int head = wv * 4 + hh;
        float e = -3.0e38f;
        if (lane < CK) {
            const float ee = s1[head * CN2 + sv] + s2[head * CN2 + dv];
            e = (ee > 0.f) ? ee : ALPHA * ee;
        }
        float m = e;
#pragma unroll
        for (int mm = 1; mm < 64; mm <<= 1) m = fmaxf(m, __shfl_xor(m, mm));
        const float p = (lane < CK) ? __expf(e - m) : 0.f;
        float s = p;
#pragma unroll
        for (int mm = 1; mm < 64; mm <<= 1) s += __shfl_xor(s, mm);
        if (lane < CK) wgt[head][lane] = p / s;
    }
    __syncthreads();

    const int c2 = tid * 2;
    float acc[CNH][2];
#pragma unroll
    for (int h = 0; h < CNH; ++h) { acc[h][0] = 0.f; acc[h][1] = 0.f; }
#pragma unroll 8
    for (int k = 0; k < CK; ++k) {
        const unsigned w2v = *reinterpret_cast<const unsigned*>(
            fb + (size_t)dsts[k] * CIN + c2);
        const float f0 = bf2f((u16)(w2v & 0xffff));
        const float f1 = bf2f((u16)(w2v >> 16));
#pragma unroll
        for (int h = 0; h < CNH; ++h) {
            const float wk = wgt[h][k];
            acc[h][0] = fmaf(wk, f0, acc[h][0]);
            acc[h][1] = fmaf(wk, f1, acc[h][1]);
        }
    }
#pragma unroll
    for (int h = 0; h < CNH; ++h) {
        const unsigned o = ((unsigned)f2bf(acc[h][1]) << 16) | f2bf(acc[h][0]);
        *reinterpret_cast<unsigned*>(gb + ((size_t)h * CN1 + t) * CIN + c2) = o;
    }
}

// ---------------------------------------------------------------------------
// fused projection + layer-2 partial GEMM.
// Block (trow, h): x = ELU(g_h[64 rows] @ W1_h)  [64x128, via MFMA, dbuf LDS]
//                  -> Xs (bf16, XOR-chunk-swizzled LDS, aliases staging bufs)
//                  -> part[h] = Xs @ W2_h        [64x128, B-frags from L2]
// ---------------------------------------------------------------------------
__global__ __launch_bounds__(256) void fusedproj_k(const u16* __restrict__ gb,
                                                   const u16* __restrict__ w1t,
                                                   const u16* __restrict__ w2t,
                                                   float* __restrict__ part) {
    __shared__ __attribute__((aligned(16))) char smem[24576];

    const int tid  = threadIdx.x;
    const int lane = tid & 63;
    const int wave = tid >> 6;
    const int trow0 = blockIdx.x * 64;
    const int h     = blockIdx.y;
    const int wr = (wave >> 1) * 32;   // 0 / 32
    const int wc = (wave & 1) * 64;    // 0 / 64

    const u16* A  = gb  + (size_t)h * CN1 * CIN;    // [2048][256]
    const u16* Bt = w1t + (size_t)h * CHID * CIN;   // [128][256]

    f32x4 acc[2][4];
#pragma unroll
    for (int m = 0; m < 2; ++m)
#pragma unroll
        for (int n = 0; n < 4; ++n) acc[m][n] = (f32x4){0.f, 0.f, 0.f, 0.f};

    const int r0c = tid >> 2;
    const int cs0 = tid & 3;
    const int c0  = (cs0 - (r0c >> 1)) & 3;
    const int r1c = r0c + 64;

    const u16* ga0 = A + (size_t)(trow0 + r0c) * CIN + c0 * 8;
    const u16* gb0 = Bt + (size_t)r0c * CIN + c0 * 8;
    const u16* gb1 = Bt + (size_t)r1c * CIN + c0 * 8;

    auto STAGE = [&](int s) {
        const int k0 = s * 32;
        char* base = smem + (s & 1) * 12288;
        u16* as = (u16*)base + wave * 512;
        u16* bs = (u16*)(base + 4096) + wave * 512;
        GLD16(ga0 + k0, as);
        GLD16(gb0 + k0, bs);
        GLD16(gb1 + k0, bs + 2048);
    };

    STAGE(0);
    __syncthreads();

    for (int s = 0; s < 8; ++s) {
        if (s + 1 < 8) STAGE(s + 1);

        const u16* Acur = (const u16*)(smem + (s & 1) * 12288);
        const u16* Bcur = Acur + 2048;

        bf16x8 af[2], bfr[4];
#pragma unroll
        for (int m = 0; m < 2; ++m) {
            const int rt = wr + m * 16 + (lane & 15);
            const int cs = ((lane >> 4) + (rt >> 1)) & 3;
            af[m] = *reinterpret_cast<const bf16x8*>(Acur + rt * 32 + cs * 8);
        }
#pragma unroll
        for (int n = 0; n < 4; ++n) {
            const int rt2 = wc + n * 16 + (lane & 15);
            const int cs2 = ((lane >> 4) + (rt2 >> 1)) & 3;
            bfr[n] = *reinterpret_cast<const bf16x8*>(Bcur + rt2 * 32 + cs2 * 8);
        }
#pragma unroll
        for (int m = 0; m < 2; ++m)
#pragma unroll
            for (int n = 0; n < 4; ++n)
                acc[m][n] = __builtin_amdgcn_mfma_f32_16x16x32_bf16(
                    af[m], bfr[n], acc[m][n], 0, 0, 0);

        __syncthreads();
    }

    // ---- ELU -> bf16 -> Xs (XOR-chunk swizzle: chunk c of row r at c^(r&7)) ----
    u16* Xs = (u16*)smem;   // 64x128 u16 = 16KB, aliases dead staging bufs
#pragma unroll
    for (int m = 0; m < 2; ++m) {
        const int rr = wr + m * 16 + (lane >> 4) * 4;
#pragma unroll
        for (int n = 0; n < 4; ++n) {
            const int cc = wc + n * 16 + (lane & 15);
#pragma unroll
            for (int q = 0; q < 4; ++q) {
                float v = acc[m][n][q];
                v = (v > 0.f) ? v : __expf(v) - 1.f;   // ELU
                const int r = rr + q;
                Xs[r * 128 + ((((cc >> 3) ^ (r & 7)) << 3) | (cc & 7))] = f2bf(v);
            }
        }
    }
    __syncthreads();

    // ---- GEMM2: part[h] = Xs @ W2_h (K=128, 4 steps; no barriers) ----
    f32x4 acc2[2][4];
#pragma unroll
    for (int m = 0; m < 2; ++m)
#pragma unroll
        for (int n = 0; n < 4; ++n) acc2[m][n] = (f32x4){0.f, 0.f, 0.f, 0.f};

#pragma unroll
    for (int ks = 0; ks < 4; ++ks) {
        bf16x8 a2f[2], b2f[4];
#pragma unroll
        for (int m = 0; m < 2; ++m) {
            const int rt = wr + m * 16 + (lane & 15);
            const int k0 = ks * 32 + (lane >> 4) * 8;
            a2f[m] = *reinterpret_cast<const bf16x8*>(
                Xs + rt * 128 + (((k0 >> 3) ^ (rt & 7)) << 3));
        }
#pragma unroll
        for (int n = 0; n < 4; ++n) {
            const int rb = wc + n * 16 + (lane & 15);   // output col
            b2f[n] = *reinterpret_cast<const bf16x8*>(
                w2t + (size_t)rb * (CNH * CHID) + h * CHID + ks * 32 + (lane >> 4) * 8);
        }
#pragma unroll
        for (int m = 0; m < 2; ++m)
#pragma unroll
            for (int n = 0; n < 4; ++n)
                acc2[m][n] = __builtin_amdgcn_mfma_f32_16x16x32_bf16(
                    a2f[m], b2f[n], acc2[m][n], 0, 0, 0);
    }

    // write part[h][trow0+r][c]  (C/D layout m89)
#pragma unroll
    for (int m = 0; m < 2; ++m) {
        const int rr = trow0 + wr + m * 16 + (lane >> 4) * 4;
#pragma unroll
        for (int n = 0; n < 4; ++n) {
            const int cc = wc + n * 16 + (lane & 15);
#pragma unroll
            for (int q = 0; q < 4; ++q)
                part[((size_t)h * CN1 + rr + q) * CHID + cc] = acc2[m][n][q];
        }
    }
}

// ---------------------------------------------------------------------------
// layer-2: reduce 8 head-partials -> h2 f32, + scores. one wave per node
// ---------------------------------------------------------------------------
__global__ __launch_bounds__(256) void scores2_k(const float* __restrict__ part,
                                                 const float* __restrict__ a,
                                                 float* __restrict__ h2,
                                                 float* __restrict__ s1,
                                                 float* __restrict__ s2) {
    const int wid  = (blockIdx.x * 256 + threadIdx.x) >> 6;   // node
    const int lane = threadIdx.x & 63;
    const int j = lane * 2;
    float x0 = 0.f, x1 = 0.f;
#pragma unroll
    for (int sp = 0; sp < 8; ++sp) {
        const float2 v = *reinterpret_cast<const float2*>(
            part + (size_t)sp * CN1 * CHID + (size_t)wid * CHID + j);
        x0 += v.x; x1 += v.y;
    }
    *reinterpret_cast<float2*>(h2 + (size_t)wid * CHID + j) = make_float2(x0, x1);
    float d1 = x0 * a[j] + x1 * a[j + 1];
    float d2 = x0 * a[CHID + j] + x1 * a[CHID + j + 1];
#pragma unroll
    for (int m = 1; m < 64; m <<= 1) {
        d1 += __shfl_xor(d1, m);
        d2 += __shfl_xor(d2, m);
    }
    if (lane == 0) { s1[wid] = d1; s2[wid] = d2; }
}

// ---------------------------------------------------------------------------
// layer-2 softmax+aggregate+ELU: one wave per target; f32 in/out
// ---------------------------------------------------------------------------
__global__ __launch_bounds__(256) void agg2_k(const float* __restrict__ s1,
                                              const float* __restrict__ s2,
                                              const int* __restrict__ src,
                                              const int* __restrict__ dst,
                                              const float* __restrict__ h2,
                                              float* __restrict__ out) {
    const int t    = (blockIdx.x * 256 + threadIdx.x) >> 6;
    const int lane = threadIdx.x & 63;

    float e = -3.0e38f;
    int dv = 0;
    if (lane < CK) {
        const int sv = src[t * CK + lane];
        dv = dst[t * CK + lane];
        const float ee = s1[sv] + s2[dv];
        e = (ee > 0.f) ? ee : ALPHA * ee;
    }
    float m = e;
#pragma unroll
    for (int mm = 1; mm < 64; mm <<= 1) m = fmaxf(m, __shfl_xor(m, mm));
    float p = (lane < CK) ? __expf(e - m) : 0.f;
    float ssum = p;
#pragma unroll
    for (int mm = 1; mm < 64; mm <<= 1) ssum += __shfl_xor(ssum, mm);
    const float invs = 1.f / ssum;

    float a0 = 0.f, a1 = 0.f;
#pragma unroll
    for (int k = 0; k < CK; ++k) {
        const float w = __shfl(p, k) * invs;
        const int d = __shfl(dv, k);
        const float2 hv = *reinterpret_cast<const float2*>(h2 + (size_t)d * CHID + lane * 2);
        a0 = fmaf(w, hv.x, a0);
        a1 = fmaf(w, hv.y, a1);
    }
    a0 = (a0 > 0.f) ? a0 : __expf(a0) - 1.f;
    a1 = (a1 > 0.f) ? a1 : __expf(a1) - 1.f;
    *reinterpret_cast<float2*>(out + (size_t)t * CHID + lane * 2) = make_float2(a0, a1);
}

// ---------------------------------------------------------------------------
extern "C" void kernel_launch(void* const* d_in, const int* in_sizes, int n_in,
                              void* d_out, int out_size, void* d_ws, size_t ws_size,
                              hipStream_t stream) {
    const float* feats = (const float*)d_in[0];
    const float* W1    = (const float*)d_in[1];
    const float* a1    = (const float*)d_in[2];
    const float* W2    = (const float*)d_in[3];
    const float* a2    = (const float*)d_in[4];
    const int*   src1  = (const int*)d_in[5];
    const int*   dst1  = (const int*)d_in[6];
    const int*   src2  = (const int*)d_in[8];
    const int*   dst2  = (const int*)d_in[9];
    float* out = (float*)d_out;

    char* w = (char*)d_ws;
    u16*   fb   = (u16*)w;                 w += (size_t)CN2 * CIN * 2;          // 4 MB
    u16*   w1t  = (u16*)w;                 w += (size_t)CNH * CIN * CHID * 2;
    u16*   w2t  = (u16*)w;                 w += (size_t)CNH * CHID * CHID * 2;
    float* pvec = (float*)w;               w += (size_t)CNH * 2 * CIN * 4;      // 16 KB
    float* s1   = (float*)w;               w += (size_t)CNH * CN2 * 4;
    float* s2   = (float*)w;               w += (size_t)CNH * CN2 * 4;
    u16*   gb   = (u16*)w;                 w += (size_t)CNH * CN1 * CIN * 2;    // 8 MB
    float* part = (float*)w;               w += (size_t)8 * CN1 * CHID * 4;     // 8 MB
    float* h2   = (float*)w;               w += (size_t)CN1 * CHID * 4;
    float* s21  = (float*)w;               w += (size_t)CN1 * 4;
    float* s22  = (float*)w;               w += (size_t)CN1 * 4;

    // ---- prep: W transposes + pvec ----
    prep2_k<<<dim3(256 + 128 + 16), 256, 0, stream>>>(W1, w1t, W2, w2t, a1, pvec);

    // ---- feats convert + all-head layer-1 scores (fused) ----
    fsc_k<<<dim3(CN2 / 4), 256, 0, stream>>>(feats, fb, pvec, s1, s2);

    // ---- layer-1 softmax + feats-aggregate -> g [8][2048][256] bf16 ----
    agg1g_k<<<dim3(CN1), 128, 0, stream>>>(s1, s2, src1, dst1, fb, gb);

    // ---- fused: x_h = ELU(g_h @ W1_h); part[h] = x_h @ W2_h ----
    fusedproj_k<<<dim3(CN1 / 64, CNH), 256, 0, stream>>>(gb, w1t, w2t, part);

    // ---- reduce partials -> h2 + layer-2 scores ----
    scores2_k<<<dim3(CN1 / 4), 256, 0, stream>>>(part, a2, h2, s21, s22);

    // ---- layer-2 softmax + aggregate + ELU ----
    agg2_k<<<dim3(CN0 / 4), 256, 0, stream>>>(s21, s22, src2, dst2, h2, out);
}